// Round 6
// baseline (364.618 us; speedup 1.0000x reference)
//
#include <hip/hip_runtime.h>

// MHSA fused pipeline: B=4 S=2048 D=128 H=8. fp32 in/out, bf16 MFMA internally.
// ws layout: xb(2MB) Wtq/Wtk/Wtv/Wot(256KB ea) | Qb(16MB) Kb(16MB) Vt(16MB) att(16MB)
// Softmax runs in log2 domain: Q projection is pre-scaled by 128^-0.25 * log2(e).

typedef __attribute__((ext_vector_type(8))) short bf16x8;
typedef __attribute__((ext_vector_type(4))) float f32x4;
typedef __attribute__((ext_vector_type(16))) float f32x16;
typedef __attribute__((ext_vector_type(4))) int i32x4;

#define LOG2E 1.4426950408889634f

__device__ __forceinline__ unsigned short f2bf(float f) {
  unsigned u = __builtin_bit_cast(unsigned, f);
  return (unsigned short)((u + 0x7fffu + ((u >> 16) & 1u)) >> 16);
}

__device__ __forceinline__ unsigned cvtpk(float lo, float hi) {
  unsigned r;
  asm("v_cvt_pk_bf16_f32 %0, %1, %2" : "=v"(r) : "v"(lo), "v"(hi));
  return r;
}

__device__ __forceinline__ float vexp2(float x) {  // raw v_exp_f32 (2^x)
  float r;
  asm("v_exp_f32 %0, %1" : "=v"(r) : "v"(x));
  return r;
}

// ---------------- prep: x -> bf16 (vectorized); W transposes via LDS tiles ----------------
__global__ __launch_bounds__(256) void prep_kernel(const float* __restrict__ x,
    const float* __restrict__ Wq, const float* __restrict__ Wk, const float* __restrict__ Wv,
    const float* __restrict__ Wo,
    unsigned short* __restrict__ xb, unsigned short* __restrict__ Wtq,
    unsigned short* __restrict__ Wtk, unsigned short* __restrict__ Wtv,
    unsigned short* __restrict__ Wot) {
  __shared__ float tl[64][68];
  int bid = blockIdx.x, t = threadIdx.x;
  if (bid < 512) {
    int idx = (bid * 256 + t) * 8;
    f32x4 a = *(const f32x4*)(x + idx);
    f32x4 b = *(const f32x4*)(x + idx + 4);
    i32x4 o;
    o[0] = (int)cvtpk(a[0], a[1]); o[1] = (int)cvtpk(a[2], a[3]);
    o[2] = (int)cvtpk(b[0], b[1]); o[3] = (int)cvtpk(b[2], b[3]);
    *(i32x4*)(xb + idx) = o;
    return;
  }
  int tb = bid - 512;
  int which = tb >> 5, tile = tb & 31;
  const float* in; unsigned short* out; int K, N, kt_, nt_;
  if (which == 0)      { in = Wq; out = Wtq; }
  else if (which == 1) { in = Wk; out = Wtk; }
  else if (which == 2) { in = Wv; out = Wtv; }
  else                 { in = Wo; out = Wot; }
  if (which < 3) { K = 128;  N = 1024; kt_ = tile >> 4; nt_ = tile & 15; }
  else           { K = 1024; N = 128;  kt_ = tile >> 1; nt_ = tile & 1; }
  int k0 = kt_ * 64, n0 = nt_ * 64;
  int tr = t >> 4, tc = (t & 15) * 4;
#pragma unroll
  for (int i = 0; i < 4; ++i) {
    f32x4 v = *(const f32x4*)(in + (k0 + tr + i * 16) * N + n0 + tc);
#pragma unroll
    for (int j = 0; j < 4; ++j) tl[tc + j][tr + i * 16] = v[j];
  }
  __syncthreads();
  int n = t >> 2, c0 = (t & 3) * 16;
  i32x4 o1, o2;
#pragma unroll
  for (int j = 0; j < 4; ++j) o1[j] = (int)cvtpk(tl[n][c0 + 2 * j], tl[n][c0 + 2 * j + 1]);
#pragma unroll
  for (int j = 0; j < 4; ++j) o2[j] = (int)cvtpk(tl[n][c0 + 8 + 2 * j], tl[n][c0 + 9 + 2 * j]);
  *(i32x4*)(out + (n0 + n) * K + k0 + c0) = o1;
  *(i32x4*)(out + (n0 + n) * K + k0 + c0 + 8) = o2;
}

// ---------------- staging helpers (row = 128 bf16 = 256B swizzled) ----------------
__device__ __forceinline__ void stage_64x128(unsigned short* dst, const unsigned short* gsrc, int t) {
#pragma unroll
  for (int it = 0; it < 4; ++it) {
    int c = t + it * 256, row = c >> 4, col = c & 15;
    *(f32x4*)((char*)dst + row * 256 + ((col * 16) ^ ((row & 7) << 4))) =
        *(const f32x4*)(gsrc + row * 128 + col * 8);
  }
}

__device__ __forceinline__ void prefetch4(f32x4* r, const unsigned short* gsrc, int t) {
#pragma unroll
  for (int it = 0; it < 4; ++it) {
    int c = t + it * 256, row = c >> 4, col = c & 15;
    r[it] = *(const f32x4*)(gsrc + row * 128 + col * 8);
  }
}

__device__ __forceinline__ void write4(unsigned short* dst, const f32x4* r, int t) {
#pragma unroll
  for (int it = 0; it < 4; ++it) {
    int c = t + it * 256, row = c >> 4, col = c & 15;
    *(f32x4*)((char*)dst + row * 256 + ((col * 16) ^ ((row & 7) << 4))) = r[it];
  }
}

// MI*16 x NI*16 tile from As/Bs (both swizzled 64x128), K=128
template<int MI, int NI>
__device__ __forceinline__ void mma_t(const unsigned short* As, const unsigned short* Bs,
                                      int am0, int bn0, int l, f32x4 (&acc)[MI][NI]) {
  int lc = l & 15, kg = l >> 4;
#pragma unroll
  for (int kc = 0; kc < 4; ++kc) {
    bf16x8 a[MI], b[NI];
#pragma unroll
    for (int mi = 0; mi < MI; ++mi) {
      int ar = am0 + mi * 16 + lc;
      a[mi] = *(const bf16x8*)((const char*)As + ar * 256 + ((kc * 64 + kg * 16) ^ ((ar & 7) << 4)));
    }
#pragma unroll
    for (int ni = 0; ni < NI; ++ni) {
      int br = bn0 + ni * 16 + lc;
      b[ni] = *(const bf16x8*)((const char*)Bs + br * 256 + ((kc * 64 + kg * 16) ^ ((br & 7) << 4)));
    }
#pragma unroll
    for (int mi = 0; mi < MI; ++mi)
#pragma unroll
      for (int ni = 0; ni < NI; ++ni)
        acc[mi][ni] = __builtin_amdgcn_mfma_f32_16x16x32_bf16(a[mi], b[ni], acc[mi][ni], 0, 0, 0);
  }
}

// ---------------- merged QKV projection: 64x64 tiles, grid (128,16) ----------------
__global__ __launch_bounds__(256, 4) void qkv_kernel(const unsigned short* __restrict__ xb,
    const unsigned short* __restrict__ Wtq, const unsigned short* __restrict__ Wtk,
    const unsigned short* __restrict__ Wtv,
    unsigned short* __restrict__ Qb, unsigned short* __restrict__ Kb,
    unsigned short* __restrict__ Vt) {
  __shared__ unsigned short Xs[64 * 128], Ws[64 * 128];
  int m0 = blockIdx.x * 64, n0 = blockIdx.y * 64;
  int t = threadIdx.x, w = t >> 6, l = t & 63;
  int wm = w & 1, wn = w >> 1, lc = l & 15, kg = l >> 4;
  stage_64x128(Xs, xb + m0 * 128, t);
  stage_64x128(Ws, Wtq + n0 * 128, t);
  __syncthreads();

  f32x4 rw[4];
  prefetch4(rw, Wtk + n0 * 128, t);   // T14: Wk tile in flight during Q-compute

  f32x4 acc[2][2];
#pragma unroll
  for (int mi = 0; mi < 2; ++mi)
#pragma unroll
    for (int ni = 0; ni < 2; ++ni) acc[mi][ni] = (f32x4){0.f, 0.f, 0.f, 0.f};
  mma_t<2, 2>(Xs, Ws, wm * 32, wn * 32, l, acc);
  const float qscale = 0.29730177875068026f * LOG2E;  // 128^-0.25 * log2(e)
#pragma unroll
  for (int mi = 0; mi < 2; ++mi)
#pragma unroll
    for (int ni = 0; ni < 2; ++ni)
#pragma unroll
      for (int e = 0; e < 4; ++e) {
        int m = m0 + wm * 32 + mi * 16 + kg * 4 + e;
        int n = n0 + wn * 32 + ni * 16 + lc;
        int b = m >> 11, s = m & 2047, h = n >> 7, d = n & 127;
        Qb[((b * 8 + h) * 2048 + s) * 128 + d] = f2bf(acc[mi][ni][e] * qscale);
      }
  __syncthreads();
  write4(Ws, rw, t);
  __syncthreads();
  prefetch4(rw, Wtv + n0 * 128, t);

#pragma unroll
  for (int mi = 0; mi < 2; ++mi)
#pragma unroll
    for (int ni = 0; ni < 2; ++ni) acc[mi][ni] = (f32x4){0.f, 0.f, 0.f, 0.f};
  mma_t<2, 2>(Xs, Ws, wm * 32, wn * 32, l, acc);
  const float kscale = 0.29730177875068026f;
#pragma unroll
  for (int mi = 0; mi < 2; ++mi)
#pragma unroll
    for (int ni = 0; ni < 2; ++ni)
#pragma unroll
      for (int e = 0; e < 4; ++e) {
        int m = m0 + wm * 32 + mi * 16 + kg * 4 + e;
        int n = n0 + wn * 32 + ni * 16 + lc;
        int b = m >> 11, s = m & 2047, h = n >> 7, d = n & 127;
        Kb[((b * 8 + h) * 2048 + s) * 128 + d] = f2bf(acc[mi][ni][e] * kscale);
      }
  __syncthreads();
  write4(Ws, rw, t);
  __syncthreads();

  // V phase, operand-swapped: A = Wv^T rows (n), B = x rows (m) -> coalesced Vt write
#pragma unroll
  for (int mi = 0; mi < 2; ++mi)
#pragma unroll
    for (int ni = 0; ni < 2; ++ni) acc[mi][ni] = (f32x4){0.f, 0.f, 0.f, 0.f};
  mma_t<2, 2>(Ws, Xs, wm * 32, wn * 32, l, acc);
#pragma unroll
  for (int mi = 0; mi < 2; ++mi)
#pragma unroll
    for (int ni = 0; ni < 2; ++ni)
#pragma unroll
      for (int e = 0; e < 4; ++e) {
        int n = n0 + wm * 32 + mi * 16 + kg * 4 + e;
        int m = m0 + wn * 32 + ni * 16 + lc;
        int b = m >> 11, s = m & 2047, h = n >> 7, d = n & 127;
        Vt[((b * 8 + h) * 128 + d) * 2048 + s] = f2bf(acc[mi][ni][e]);
      }
}

// ---------------- flash attention: 8 waves, kv-row-split (g = wave>>2), merge epilogue ----
// Wave (g, wl): q-rows qt*128 + wl*32, kv rows g*32..g*32+32 of every 64-row tile.
// Per tile per wave: 8 QK MFMA + 8 PV MFMA, 16 exp/lane. Partials merged at end via LDS.
// LDS map: buf b at b*32768: K 64x256B swizzled [0,16384) | V^T 128x128B swizzled [16384,32768)
__device__ __forceinline__ void qk_step8(const char* Kb_, const bf16x8* qf, int kr, int hi,
                                         f32x16& s0) {
#pragma unroll
  for (int j = 0; j < 16; ++j) s0[j] = 0.f;
#pragma unroll
  for (int kc = 0; kc < 8; ++kc) {
    int cb = kc * 32 + hi * 16;
    bf16x8 k0 = *(const bf16x8*)(Kb_ + kr * 256 + (cb ^ ((kr & 7) << 4)));
    s0 = __builtin_amdgcn_mfma_f32_32x32x16_bf16(k0, qf[kc], s0, 0, 0, 0);
  }
}

__global__ __launch_bounds__(512, 4) void attn_kernel(const unsigned short* __restrict__ Qb,
    const unsigned short* __restrict__ Kb, const unsigned short* __restrict__ Vt,
    unsigned short* __restrict__ att) {
  __shared__ __align__(16) char smem[67584];  // 2 bufs x {K 16KB, V^T 16KB} | merge overlay
  int bid = blockIdx.x;
  int fid = (bid & 7) * 64 + (bid >> 3);      // XCD swizzle (512 % 8 == 0 -> bijective)
  int bh = fid >> 4, qt = fid & 15;
  const unsigned short* Qp = Qb + bh * 2048 * 128;
  const unsigned short* Kp = Kb + bh * 2048 * 128;
  const unsigned short* Vp = Vt + bh * 128 * 2048;
  int t = threadIdx.x, w = t >> 6, l = t & 63, lc = l & 31, hi = l >> 5;
  int g = w >> 2, wl = w & 3;
  int q0 = qt * 128 + wl * 32;
  int kr = g * 32 + lc;                       // K LDS row this wave consumes

  // Q fragments (B-operand): lane l -> Q[q0+lc][kc*16 + hi*8 + j]
  bf16x8 qf[8];
  {
    const unsigned short* qr_ = Qp + (q0 + lc) * 128 + hi * 8;
#pragma unroll
    for (int kc = 0; kc < 8; ++kc) qf[kc] = *(const bf16x8*)(qr_ + kc * 16);
  }

  // staging geometry: 8 waves split K(64 rows) and V^T(128 rows)
  int kcol = l & 15, vc = l & 7;
  int krow[2], vrow[2];
#pragma unroll
  for (int i = 0; i < 2; ++i) { krow[i] = w * 8 + i * 4 + (l >> 4); vrow[i] = w * 16 + i * 8 + (l >> 3); }

  f32x16 acc[4];
#pragma unroll
  for (int i = 0; i < 4; ++i)
#pragma unroll
    for (int j = 0; j < 16; ++j) acc[i][j] = 0.f;
  float m_run = -1e30f, l_run = 0.f;

  f32x4 sk[2], sv[2];
#pragma unroll
  for (int i = 0; i < 2; ++i) {
    sk[i] = *(const f32x4*)(Kp + krow[i] * 128 + kcol * 8);
    sv[i] = *(const f32x4*)(Vp + vrow[i] * 2048 + vc * 8);
  }
#pragma unroll
  for (int i = 0; i < 2; ++i) {
    *(f32x4*)(smem + krow[i] * 256 + ((kcol * 16) ^ ((krow[i] & 7) << 4))) = sk[i];
    *(f32x4*)(smem + 16384 + vrow[i] * 128 + ((vc * 16) ^ ((vrow[i] & 7) << 4))) = sv[i];
  }
#pragma unroll
  for (int i = 0; i < 2; ++i) {
    sk[i] = *(const f32x4*)(Kp + (64 + krow[i]) * 128 + kcol * 8);
    sv[i] = *(const f32x4*)(Vp + vrow[i] * 2048 + 64 + vc * 8);
  }
  __syncthreads();
  f32x16 s0;
  qk_step8(smem, qf, kr, hi, s0);

  for (int kt = 0; kt < 32; ++kt) {
    int nb = (kt + 1) & 1;

    // ---- softmax(kt), log2 domain, 16 values/lane ----
    float t4[4];
#pragma unroll
    for (int j = 0; j < 4; ++j)
      t4[j] = fmaxf(fmaxf(s0[j], s0[j + 4]), fmaxf(s0[j + 8], s0[j + 12]));
    float pmax = fmaxf(fmaxf(t4[0], t4[1]), fmaxf(t4[2], t4[3]));
    pmax = fmaxf(pmax, __shfl_xor(pmax, 32));
    float mold = m_run;
    bool defer = (__all(pmax <= m_run + 11.5416f) != 0);   // T13 in log2 units
    if (!defer) m_run = fmaxf(m_run, pmax);
#pragma unroll
    for (int j = 0; j < 16; ++j) s0[j] = vexp2(s0[j] - m_run);
    float q4[4];
#pragma unroll
    for (int j = 0; j < 4; ++j)
      q4[j] = (s0[j] + s0[j + 4]) + (s0[j + 8] + s0[j + 12]);
    float rs = (q4[0] + q4[1]) + (q4[2] + q4[3]);
    rs += __shfl_xor(rs, 32);
    if (!defer) {
      float resc = vexp2(mold - m_run);
      l_run = l_run * resc + rs;
#pragma unroll
      for (int r = 0; r < 16; ++r) {
        int qr = (r & 3) + 8 * (r >> 2) + 4 * hi;
        float f = __shfl(resc, qr, 32);
#pragma unroll
        for (int dt = 0; dt < 4; ++dt) acc[dt][r] *= f;
      }
    } else {
      l_run += rs;
    }

    // ---- pack P -> PV A-frags via cvt_pk + permlane32_swap (T12) ----
    bf16x8 pa[2];
#define PACK(ks, SX, o) { \
      unsigned x1 = cvtpk(SX[o], SX[(o) + 1]); \
      unsigned y1 = cvtpk(SX[(o) + 4], SX[(o) + 5]); \
      unsigned x2 = cvtpk(SX[(o) + 2], SX[(o) + 3]); \
      unsigned y2 = cvtpk(SX[(o) + 6], SX[(o) + 7]); \
      asm("v_permlane32_swap_b32 %0, %1" : "+v"(x1), "+v"(y1)); \
      asm("v_permlane32_swap_b32 %0, %1" : "+v"(x2), "+v"(y2)); \
      i32x4 pp; \
      pp[0] = (int)x1; pp[1] = (int)x2; pp[2] = (int)y1; pp[3] = (int)y2; \
      pa[ks] = __builtin_bit_cast(bf16x8, pp); }
    PACK(0, s0, 0) PACK(1, s0, 8)
#undef PACK

    // ---- stage tile kt+1 into buf[nb]; issue loads for kt+2 ----
    __syncthreads();
    if (kt < 31) {
      char* Kn = smem + (nb << 15);
      char* Vn = Kn + 16384;
#pragma unroll
      for (int i = 0; i < 2; ++i) {
        *(f32x4*)(Kn + krow[i] * 256 + ((kcol * 16) ^ ((krow[i] & 7) << 4))) = sk[i];
        *(f32x4*)(Vn + vrow[i] * 128 + ((vc * 16) ^ ((vrow[i] & 7) << 4))) = sv[i];
      }
      if (kt < 30) {
        int kv0 = (kt + 2) * 64;
#pragma unroll
        for (int i = 0; i < 2; ++i) {
          sk[i] = *(const f32x4*)(Kp + (kv0 + krow[i]) * 128 + kcol * 8);
          sv[i] = *(const f32x4*)(Vp + vrow[i] * 2048 + kv0 + vc * 8);
        }
      }
    }
    __syncthreads();

    // ---- contiguous MFMA cluster: QK(kt+1) then PV(kt) ----
    __builtin_amdgcn_s_setprio(1);
    if (kt < 31) qk_step8(smem + (nb << 15), qf, kr, hi, s0);
    const char* Vb_ = smem + ((kt & 1) << 15) + 16384;
#pragma unroll
    for (int ks = 0; ks < 2; ++ks) {
      int cb = g * 64 + ks * 32 + hi * 16;
#pragma unroll
      for (int dt = 0; dt < 4; ++dt) {
        int vr = dt * 32 + lc;
        bf16x8 vb = *(const bf16x8*)(Vb_ + vr * 128 + (cb ^ ((vr & 7) << 4)));
        acc[dt] = __builtin_amdgcn_mfma_f32_32x32x16_bf16(pa[ks], vb, acc[dt], 0, 0, 0);
      }
    }
    __builtin_amdgcn_s_setprio(0);
  }

  // ---- merge the two kv-half partials, write output ----
  __syncthreads();
  float* sO = (float*)smem;                   // [wl][dt][r][lane] = 4x4x16x64 f32 = 64KB
  float* sm = (float*)(smem + 65536);
  float* sl = (float*)(smem + 66560);
  if (g == 1) {
    int base = wl * 4096 + l;
#pragma unroll
    for (int dt = 0; dt < 4; ++dt)
#pragma unroll
      for (int r = 0; r < 16; ++r)
        sO[base + dt * 1024 + r * 64] = acc[dt][r];
    sm[wl * 64 + l] = m_run;
    sl[wl * 64 + l] = l_run;
  }
  __syncthreads();
  if (g == 0) {
    float m1 = sm[wl * 64 + l], l1 = sl[wl * 64 + l];
    float M = fmaxf(m_run, m1);
    float w0 = vexp2(m_run - M), w1 = vexp2(m1 - M);
    float lsum = l_run * w0 + l1 * w1;
    int b = bh >> 3, h = bh & 7;
    int base = wl * 4096 + l;
#pragma unroll
    for (int r = 0; r < 16; ++r) {
      int qr = (r & 3) + 8 * (r >> 2) + 4 * hi;
      float f0 = __shfl(w0, qr, 32);
      float f1 = __shfl(w1, qr, 32);
      float li = 1.f / __shfl(lsum, qr, 32);
      unsigned short* orow = att + ((b * 2048 + (q0 + qr)) * 8 + h) * 128 + lc;
#pragma unroll
      for (int dt = 0; dt < 4; ++dt)
        orow[dt * 32] = f2bf((acc[dt][r] * f0 + sO[base + dt * 1024 + r * 64] * f1) * li);
    }
  }
}

// 64x64 output tile from As(64x128) x Bs(64x128)^T, both swizzled
__device__ __forceinline__ void mfma_64x64(const unsigned short* As, const unsigned short* Bs,
                                           int w, int l, f32x4 acc[4]) {
  int lc = l & 15, kg = l >> 4;
#pragma unroll
  for (int kc = 0; kc < 4; ++kc) {
    int ar = w * 16 + lc;
    bf16x8 a = *(const bf16x8*)((const char*)As + ar * 256 + ((kc * 64 + kg * 16) ^ ((ar & 7) << 4)));
#pragma unroll
    for (int tt = 0; tt < 4; ++tt) {
      int br = tt * 16 + lc;
      bf16x8 b = *(const bf16x8*)((const char*)Bs + br * 256 + ((kc * 64 + kg * 16) ^ ((br & 7) << 4)));
      acc[tt] = __builtin_amdgcn_mfma_f32_16x16x32_bf16(a, b, acc[tt], 0, 0, 0);
    }
  }
}

// ---------------- output projection: out = att @ Wo + bo (fp32 out) ----------------
__global__ __launch_bounds__(256) void out_proj_kernel(const unsigned short* __restrict__ att,
    const unsigned short* __restrict__ Wot, const float* __restrict__ bo,
    float* __restrict__ out) {
  __shared__ unsigned short As[64 * 128], Bs[64 * 128];
  int m0 = blockIdx.x * 64, n0 = blockIdx.y * 64;
  int t = threadIdx.x, w = t >> 6, l = t & 63, lc = l & 15, kg = l >> 4;
  f32x4 acc[4];
#pragma unroll
  for (int i = 0; i < 4; ++i) acc[i] = (f32x4){0.f, 0.f, 0.f, 0.f};
  f32x4 ra[4], rb[4];
#pragma unroll
  for (int it = 0; it < 4; ++it) {
    int c = t + it * 256, row = c >> 4, col = c & 15;
    ra[it] = *(const f32x4*)(att + (m0 + row) * 1024 + col * 8);
    rb[it] = *(const f32x4*)(Wot + (n0 + row) * 1024 + col * 8);
  }
  for (int kt = 0; kt < 8; ++kt) {
    if (kt) __syncthreads();
#pragma unroll
    for (int it = 0; it < 4; ++it) {
      int c = t + it * 256, row = c >> 4, col = c & 15;
      *(f32x4*)((char*)As + row * 256 + ((col * 16) ^ ((row & 7) << 4))) = ra[it];
      *(f32x4*)((char*)Bs + row * 256 + ((col * 16) ^ ((row & 7) << 4))) = rb[it];
    }
    __syncthreads();
    if (kt < 7) {
#pragma unroll
      for (int it = 0; it < 4; ++it) {
        int c = t + it * 256, row = c >> 4, col = c & 15;
        ra[it] = *(const f32x4*)(att + (m0 + row) * 1024 + (kt + 1) * 128 + col * 8);
        rb[it] = *(const f32x4*)(Wot + (n0 + row) * 1024 + (kt + 1) * 128 + col * 8);
      }
    }
    mfma_64x64(As, Bs, w, l, acc);
  }
#pragma unroll
  for (int tt = 0; tt < 4; ++tt)
#pragma unroll
    for (int e = 0; e < 4; ++e) {
      int m = m0 + w * 16 + kg * 4 + e;
      int n = n0 + tt * 16 + lc;
      out[m * 128 + n] = acc[tt][e] + bo[n];
    }
}

extern "C" void kernel_launch(void* const* d_in, const int* in_sizes, int n_in,
                              void* d_out, int out_size, void* d_ws, size_t ws_size,
                              hipStream_t stream) {
  const float* x  = (const float*)d_in[0];
  const float* Wq = (const float*)d_in[1];
  const float* Wk = (const float*)d_in[2];
  const float* Wv = (const float*)d_in[3];
  const float* Wo = (const float*)d_in[4];
  const float* bo = (const float*)d_in[5];
  float* out = (float*)d_out;
  char* ws = (char*)d_ws;
  unsigned short* xb  = (unsigned short*)(ws);
  unsigned short* Wtq = (unsigned short*)(ws + (2u << 20));
  unsigned short* Wtk = (unsigned short*)(ws + (2u << 20) + (256u << 10));
  unsigned short* Wtv = (unsigned short*)(ws + (2u << 20) + (512u << 10));
  unsigned short* Wot = (unsigned short*)(ws + (2u << 20) + (768u << 10));
  unsigned short* Qb  = (unsigned short*)(ws + (3u << 20));
  unsigned short* Kb  = (unsigned short*)(ws + (3u << 20) + (16u << 20));
  unsigned short* Vt  = (unsigned short*)(ws + (3u << 20) + (32u << 20));
  unsigned short* att = (unsigned short*)(ws + (3u << 20) + (48u << 20));

  hipLaunchKernelGGL(prep_kernel, dim3(640), dim3(256), 0, stream,
                     x, Wq, Wk, Wv, Wo, xb, Wtq, Wtk, Wtv, Wot);
  hipLaunchKernelGGL(qkv_kernel, dim3(128, 16), dim3(256), 0, stream,
                     xb, Wtq, Wtk, Wtv, Qb, Kb, Vt);
  hipLaunchKernelGGL(attn_kernel, dim3(512), dim3(512), 0, stream,
                     Qb, Kb, Vt, att);
  hipLaunchKernelGGL(out_proj_kernel, dim3(128, 2), dim3(256), 0, stream,
                     att, Wot, bo, out);
}

// Round 8
// 216.614 us; speedup vs baseline: 1.6833x; 1.6833x over previous
//
#include <hip/hip_runtime.h>

// MHSA fused pipeline: B=4 S=2048 D=128 H=8. fp32 in/out, bf16 MFMA internally.
// ws layout: xb(2MB) Wtq/Wtk/Wtv/Wot(256KB ea) | Qb(16MB) Kb(16MB) Vt(16MB) att(16MB)
// Softmax runs in log2 domain: Q projection is pre-scaled by 128^-0.25 * log2(e).
// Barriers: raw s_barrier + lgkmcnt(0) only (NO vmcnt drain) so global prefetch
// loads stay in flight across barriers; ds_write gets a counted vmcnt via reg deps.

typedef __attribute__((ext_vector_type(8))) short bf16x8;
typedef __attribute__((ext_vector_type(4))) float f32x4;
typedef __attribute__((ext_vector_type(16))) float f32x16;
typedef __attribute__((ext_vector_type(4))) int i32x4;

#define LOG2E 1.4426950408889634f

__device__ __forceinline__ void wg_barrier() {   // __syncthreads minus the vmcnt(0) drain
  asm volatile("s_waitcnt lgkmcnt(0)" ::: "memory");
  __builtin_amdgcn_s_barrier();
}

__device__ __forceinline__ unsigned short f2bf(float f) {
  unsigned u = __builtin_bit_cast(unsigned, f);
  return (unsigned short)((u + 0x7fffu + ((u >> 16) & 1u)) >> 16);
}

__device__ __forceinline__ unsigned cvtpk(float lo, float hi) {
  unsigned r;
  asm("v_cvt_pk_bf16_f32 %0, %1, %2" : "=v"(r) : "v"(lo), "v"(hi));
  return r;
}

__device__ __forceinline__ float vexp2(float x) {  // raw v_exp_f32 (2^x)
  float r;
  asm("v_exp_f32 %0, %1" : "=v"(r) : "v"(x));
  return r;
}

// ---------------- prep: x -> bf16 (vectorized); W transposes via LDS tiles ----------------
__global__ __launch_bounds__(256) void prep_kernel(const float* __restrict__ x,
    const float* __restrict__ Wq, const float* __restrict__ Wk, const float* __restrict__ Wv,
    const float* __restrict__ Wo,
    unsigned short* __restrict__ xb, unsigned short* __restrict__ Wtq,
    unsigned short* __restrict__ Wtk, unsigned short* __restrict__ Wtv,
    unsigned short* __restrict__ Wot) {
  __shared__ float tl[64][68];
  int bid = blockIdx.x, t = threadIdx.x;
  if (bid < 512) {
    int idx = (bid * 256 + t) * 8;
    f32x4 a = *(const f32x4*)(x + idx);
    f32x4 b = *(const f32x4*)(x + idx + 4);
    i32x4 o;
    o[0] = (int)cvtpk(a[0], a[1]); o[1] = (int)cvtpk(a[2], a[3]);
    o[2] = (int)cvtpk(b[0], b[1]); o[3] = (int)cvtpk(b[2], b[3]);
    *(i32x4*)(xb + idx) = o;
    return;
  }
  int tb = bid - 512;
  int which = tb >> 5, tile = tb & 31;
  const float* in; unsigned short* out; int K, N, kt_, nt_;
  if (which == 0)      { in = Wq; out = Wtq; }
  else if (which == 1) { in = Wk; out = Wtk; }
  else if (which == 2) { in = Wv; out = Wtv; }
  else                 { in = Wo; out = Wot; }
  if (which < 3) { K = 128;  N = 1024; kt_ = tile >> 4; nt_ = tile & 15; }
  else           { K = 1024; N = 128;  kt_ = tile >> 1; nt_ = tile & 1; }
  int k0 = kt_ * 64, n0 = nt_ * 64;
  int tr = t >> 4, tc = (t & 15) * 4;
#pragma unroll
  for (int i = 0; i < 4; ++i) {
    f32x4 v = *(const f32x4*)(in + (k0 + tr + i * 16) * N + n0 + tc);
#pragma unroll
    for (int j = 0; j < 4; ++j) tl[tc + j][tr + i * 16] = v[j];
  }
  __syncthreads();
  int n = t >> 2, c0 = (t & 3) * 16;
  i32x4 o1, o2;
#pragma unroll
  for (int j = 0; j < 4; ++j) o1[j] = (int)cvtpk(tl[n][c0 + 2 * j], tl[n][c0 + 2 * j + 1]);
#pragma unroll
  for (int j = 0; j < 4; ++j) o2[j] = (int)cvtpk(tl[n][c0 + 8 + 2 * j], tl[n][c0 + 9 + 2 * j]);
  *(i32x4*)(out + (n0 + n) * K + k0 + c0) = o1;
  *(i32x4*)(out + (n0 + n) * K + k0 + c0 + 8) = o2;
}

// ---------------- staging helpers (row = 128 bf16 = 256B swizzled) ----------------
__device__ __forceinline__ void stage_64x128(unsigned short* dst, const unsigned short* gsrc, int t) {
#pragma unroll
  for (int it = 0; it < 4; ++it) {
    int c = t + it * 256, row = c >> 4, col = c & 15;
    *(f32x4*)((char*)dst + row * 256 + ((col * 16) ^ ((row & 7) << 4))) =
        *(const f32x4*)(gsrc + row * 128 + col * 8);
  }
}

__device__ __forceinline__ void prefetch4(f32x4* r, const unsigned short* gsrc, int t) {
#pragma unroll
  for (int it = 0; it < 4; ++it) {
    int c = t + it * 256, row = c >> 4, col = c & 15;
    r[it] = *(const f32x4*)(gsrc + row * 128 + col * 8);
  }
}

__device__ __forceinline__ void write4(unsigned short* dst, const f32x4* r, int t) {
#pragma unroll
  for (int it = 0; it < 4; ++it) {
    int c = t + it * 256, row = c >> 4, col = c & 15;
    *(f32x4*)((char*)dst + row * 256 + ((col * 16) ^ ((row & 7) << 4))) = r[it];
  }
}

// MI*16 x NI*16 tile from As/Bs (both swizzled 64x128), K=128
template<int MI, int NI>
__device__ __forceinline__ void mma_t(const unsigned short* As, const unsigned short* Bs,
                                      int am0, int bn0, int l, f32x4 (&acc)[MI][NI]) {
  int lc = l & 15, kg = l >> 4;
#pragma unroll
  for (int kc = 0; kc < 4; ++kc) {
    bf16x8 a[MI], b[NI];
#pragma unroll
    for (int mi = 0; mi < MI; ++mi) {
      int ar = am0 + mi * 16 + lc;
      a[mi] = *(const bf16x8*)((const char*)As + ar * 256 + ((kc * 64 + kg * 16) ^ ((ar & 7) << 4)));
    }
#pragma unroll
    for (int ni = 0; ni < NI; ++ni) {
      int br = bn0 + ni * 16 + lc;
      b[ni] = *(const bf16x8*)((const char*)Bs + br * 256 + ((kc * 64 + kg * 16) ^ ((br & 7) << 4)));
    }
#pragma unroll
    for (int mi = 0; mi < MI; ++mi)
#pragma unroll
      for (int ni = 0; ni < NI; ++ni)
        acc[mi][ni] = __builtin_amdgcn_mfma_f32_16x16x32_bf16(a[mi], b[ni], acc[mi][ni], 0, 0, 0);
  }
}

// ---------------- merged QKV projection: 64x64 tiles, grid (128,16) ----------------
__global__ __launch_bounds__(256, 4) void qkv_kernel(const unsigned short* __restrict__ xb,
    const unsigned short* __restrict__ Wtq, const unsigned short* __restrict__ Wtk,
    const unsigned short* __restrict__ Wtv,
    unsigned short* __restrict__ Qb, unsigned short* __restrict__ Kb,
    unsigned short* __restrict__ Vt) {
  __shared__ unsigned short Xs[64 * 128], Ws[64 * 128];
  int m0 = blockIdx.x * 64, n0 = blockIdx.y * 64;
  int t = threadIdx.x, w = t >> 6, l = t & 63;
  int wm = w & 1, wn = w >> 1, lc = l & 15, kg = l >> 4;
  stage_64x128(Xs, xb + m0 * 128, t);
  stage_64x128(Ws, Wtq + n0 * 128, t);
  wg_barrier();

  f32x4 rw[4];
  prefetch4(rw, Wtk + n0 * 128, t);   // stays in flight (no vmcnt drain at barriers)

  f32x4 acc[2][2];
#pragma unroll
  for (int mi = 0; mi < 2; ++mi)
#pragma unroll
    for (int ni = 0; ni < 2; ++ni) acc[mi][ni] = (f32x4){0.f, 0.f, 0.f, 0.f};
  mma_t<2, 2>(Xs, Ws, wm * 32, wn * 32, l, acc);
  const float qscale = 0.29730177875068026f * LOG2E;  // 128^-0.25 * log2(e)
#pragma unroll
  for (int mi = 0; mi < 2; ++mi)
#pragma unroll
    for (int ni = 0; ni < 2; ++ni)
#pragma unroll
      for (int e = 0; e < 4; ++e) {
        int m = m0 + wm * 32 + mi * 16 + kg * 4 + e;
        int n = n0 + wn * 32 + ni * 16 + lc;
        int b = m >> 11, s = m & 2047, h = n >> 7, d = n & 127;
        Qb[((b * 8 + h) * 2048 + s) * 128 + d] = f2bf(acc[mi][ni][e] * qscale);
      }
  wg_barrier();
  write4(Ws, rw, t);                  // counted vmcnt wait happens here via reg dep
  wg_barrier();
  prefetch4(rw, Wtv + n0 * 128, t);

#pragma unroll
  for (int mi = 0; mi < 2; ++mi)
#pragma unroll
    for (int ni = 0; ni < 2; ++ni) acc[mi][ni] = (f32x4){0.f, 0.f, 0.f, 0.f};
  mma_t<2, 2>(Xs, Ws, wm * 32, wn * 32, l, acc);
  const float kscale = 0.29730177875068026f;
#pragma unroll
  for (int mi = 0; mi < 2; ++mi)
#pragma unroll
    for (int ni = 0; ni < 2; ++ni)
#pragma unroll
      for (int e = 0; e < 4; ++e) {
        int m = m0 + wm * 32 + mi * 16 + kg * 4 + e;
        int n = n0 + wn * 32 + ni * 16 + lc;
        int b = m >> 11, s = m & 2047, h = n >> 7, d = n & 127;
        Kb[((b * 8 + h) * 2048 + s) * 128 + d] = f2bf(acc[mi][ni][e] * kscale);
      }
  wg_barrier();
  write4(Ws, rw, t);
  wg_barrier();

  // V phase, operand-swapped: A = Wv^T rows (n), B = x rows (m) -> coalesced Vt write
#pragma unroll
  for (int mi = 0; mi < 2; ++mi)
#pragma unroll
    for (int ni = 0; ni < 2; ++ni) acc[mi][ni] = (f32x4){0.f, 0.f, 0.f, 0.f};
  mma_t<2, 2>(Ws, Xs, wm * 32, wn * 32, l, acc);
#pragma unroll
  for (int mi = 0; mi < 2; ++mi)
#pragma unroll
    for (int ni = 0; ni < 2; ++ni)
#pragma unroll
      for (int e = 0; e < 4; ++e) {
        int n = n0 + wm * 32 + mi * 16 + kg * 4 + e;
        int m = m0 + wn * 32 + ni * 16 + lc;
        int b = m >> 11, s = m & 2047, h = n >> 7, d = n & 127;
        Vt[((b * 8 + h) * 128 + d) * 2048 + s] = f2bf(acc[mi][ni][e]);
      }
}

// ---------------- flash attention: 4 waves x 32 q-rows, deep-pipelined staging ----------------
// Iter kt: [issue loads tile kt+2] softmax(kt) PACK | barrier |
//          ds_write (tile kt+1) | barrier | setprio{ QK(kt+1) + PV(kt) }.
// Loads have a full iteration of lead; barriers never drain vmcnt.
__device__ __forceinline__ void qk_step(const char* Kb_, const bf16x8* qf, int lc, int hi,
                                        f32x16& s0, f32x16& s1) {
#pragma unroll
  for (int j = 0; j < 16; ++j) { s0[j] = 0.f; s1[j] = 0.f; }
  int r1 = 32 + lc;
#pragma unroll
  for (int kc = 0; kc < 8; ++kc) {
    int cb = kc * 32 + hi * 16;
    bf16x8 k0 = *(const bf16x8*)(Kb_ + lc * 256 + (cb ^ ((lc & 7) << 4)));
    bf16x8 k1 = *(const bf16x8*)(Kb_ + r1 * 256 + (cb ^ ((r1 & 7) << 4)));
    s0 = __builtin_amdgcn_mfma_f32_32x32x16_bf16(k0, qf[kc], s0, 0, 0, 0);
    s1 = __builtin_amdgcn_mfma_f32_32x32x16_bf16(k1, qf[kc], s1, 0, 0, 0);
  }
}

__device__ __forceinline__ void attn_load(f32x4 (&sk)[4], f32x4 (&sv)[4],
    const unsigned short* Kp, const unsigned short* Vp, int kv0,
    const int (&krow)[4], const int (&vrow)[4], int kcol, int vc) {
#pragma unroll
  for (int i = 0; i < 4; ++i) {
    sk[i] = *(const f32x4*)(Kp + (kv0 + krow[i]) * 128 + kcol * 8);
    sv[i] = *(const f32x4*)(Vp + vrow[i] * 2048 + kv0 + vc * 8);
  }
}

__device__ __forceinline__ void attn_write(const f32x4 (&sk)[4], const f32x4 (&sv)[4],
    char* base, const int (&krow)[4], const int (&vrow)[4], int kcol, int vc) {
#pragma unroll
  for (int i = 0; i < 4; ++i) {
    *(f32x4*)(base + krow[i] * 256 + ((kcol * 16) ^ ((krow[i] & 7) << 4))) = sk[i];
    *(f32x4*)(base + 16384 + vrow[i] * 128 + ((vc * 16) ^ ((vrow[i] & 7) << 4))) = sv[i];
  }
}

__global__ __launch_bounds__(256, 2) void attn_kernel(const unsigned short* __restrict__ Qb,
    const unsigned short* __restrict__ Kb, const unsigned short* __restrict__ Vt,
    unsigned short* __restrict__ att) {
  __shared__ __align__(16) char smem[65536];  // buf b at b*32768: K 64x256B | V^T 128x128B
  int bid = blockIdx.x;
  int fid = (bid & 7) * 64 + (bid >> 3);      // XCD swizzle (512 % 8 == 0 -> bijective)
  int bh = fid >> 4, qt = fid & 15;
  const unsigned short* Qp = Qb + bh * 2048 * 128;
  const unsigned short* Kp = Kb + bh * 2048 * 128;
  const unsigned short* Vp = Vt + bh * 128 * 2048;
  int t = threadIdx.x, w = t >> 6, l = t & 63, lc = l & 31, hi = l >> 5;
  int q0 = qt * 128 + w * 32;

  // Q fragments (B-operand): lane l -> Q[q0+lc][kc*16 + hi*8 + j]
  bf16x8 qf[8];
  {
    const unsigned short* qr_ = Qp + (q0 + lc) * 128 + hi * 8;
#pragma unroll
    for (int kc = 0; kc < 8; ++kc) qf[kc] = *(const bf16x8*)(qr_ + kc * 16);
  }

  int kcol = l & 15, vc = l & 7;
  int krow[4], vrow[4];
#pragma unroll
  for (int i = 0; i < 4; ++i) { krow[i] = w * 16 + i * 4 + (l >> 4); vrow[i] = w * 32 + i * 8 + (l >> 3); }

  f32x16 acc[4];
#pragma unroll
  for (int i = 0; i < 4; ++i)
#pragma unroll
    for (int j = 0; j < 16; ++j) acc[i][j] = 0.f;
  float m_run = -1e30f, l_run = 0.f;

  f32x4 skA[4], svA[4], skB[4], svB[4];
  // prologue: tile0 -> A -> buf0; tile1 -> B (in flight); QK(0)
  attn_load(skA, svA, Kp, Vp, 0, krow, vrow, kcol, vc);
  attn_write(skA, svA, smem, krow, vrow, kcol, vc);
  attn_load(skB, svB, Kp, Vp, 64, krow, vrow, kcol, vc);
  wg_barrier();
  f32x16 s0, s1;
  qk_step(smem, qf, lc, hi, s0, s1);

#define PACK(ks, SX, o) { \
      unsigned x1 = cvtpk(SX[o], SX[(o) + 1]); \
      unsigned y1 = cvtpk(SX[(o) + 4], SX[(o) + 5]); \
      unsigned x2 = cvtpk(SX[(o) + 2], SX[(o) + 3]); \
      unsigned y2 = cvtpk(SX[(o) + 6], SX[(o) + 7]); \
      asm("v_permlane32_swap_b32 %0, %1" : "+v"(x1), "+v"(y1)); \
      asm("v_permlane32_swap_b32 %0, %1" : "+v"(x2), "+v"(y2)); \
      i32x4 pp; \
      pp[0] = (int)x1; pp[1] = (int)x2; pp[2] = (int)y1; pp[3] = (int)y2; \
      pa[ks] = __builtin_bit_cast(bf16x8, pp); }

#pragma unroll 1
  for (int kt2 = 0; kt2 < 32; kt2 += 2) {
    // even iter: load -> A (tile kt2+2), write B (tile kt2+1)
    {
      int kt = kt2;
      if (kt < 30) attn_load(skA, svA, Kp, Vp, (kt + 2) * 64, krow, vrow, kcol, vc);
      float t8[8];
#pragma unroll
      for (int j = 0; j < 8; ++j)
        t8[j] = fmaxf(fmaxf(s0[j], s0[j + 8]), fmaxf(s1[j], s1[j + 8]));
      float pmax = fmaxf(fmaxf(fmaxf(t8[0], t8[1]), fmaxf(t8[2], t8[3])),
                         fmaxf(fmaxf(t8[4], t8[5]), fmaxf(t8[6], t8[7])));
      pmax = fmaxf(pmax, __shfl_xor(pmax, 32));
      float mold = m_run;
      bool defer = (__all(pmax <= m_run + 11.5416f) != 0);
      if (!defer) m_run = fmaxf(m_run, pmax);
#pragma unroll
      for (int j = 0; j < 16; ++j) s0[j] = vexp2(s0[j] - m_run);
#pragma unroll
      for (int j = 0; j < 16; ++j) s1[j] = vexp2(s1[j] - m_run);
      float q8[8];
#pragma unroll
      for (int j = 0; j < 8; ++j) q8[j] = (s0[j] + s0[j + 8]) + (s1[j] + s1[j + 8]);
      float rs = ((q8[0] + q8[1]) + (q8[2] + q8[3])) + ((q8[4] + q8[5]) + (q8[6] + q8[7]));
      rs += __shfl_xor(rs, 32);
      if (!defer) {
        float resc = vexp2(mold - m_run);
        l_run = l_run * resc + rs;
#pragma unroll
        for (int r = 0; r < 16; ++r) {
          int qr = (r & 3) + 8 * (r >> 2) + 4 * hi;
          float f = __shfl(resc, qr, 32);
#pragma unroll
          for (int dt = 0; dt < 4; ++dt) acc[dt][r] *= f;
        }
      } else {
        l_run += rs;
      }
      bf16x8 pa[4];
      PACK(0, s0, 0) PACK(1, s0, 8) PACK(2, s1, 0) PACK(3, s1, 8)
      wg_barrier();
      attn_write(skB, svB, smem + 32768, krow, vrow, kcol, vc);  // tile kt+1 (odd buf)
      wg_barrier();
      __builtin_amdgcn_s_setprio(1);
      qk_step(smem + 32768, qf, lc, hi, s0, s1);
      const char* Vb_ = smem + 16384;   // buf0 V (tile kt, even)
#pragma unroll
      for (int ks = 0; ks < 4; ++ks) {
        int cb = ks * 32 + hi * 16;
#pragma unroll
        for (int dt = 0; dt < 4; ++dt) {
          int vr = dt * 32 + lc;
          bf16x8 vb = *(const bf16x8*)(Vb_ + vr * 128 + (cb ^ ((vr & 7) << 4)));
          acc[dt] = __builtin_amdgcn_mfma_f32_32x32x16_bf16(pa[ks], vb, acc[dt], 0, 0, 0);
        }
      }
      __builtin_amdgcn_s_setprio(0);
    }
    // odd iter: load -> B (tile kt2+3), write A (tile kt2+2)
    {
      int kt = kt2 + 1;
      if (kt < 30) attn_load(skB, svB, Kp, Vp, (kt + 2) * 64, krow, vrow, kcol, vc);
      float t8[8];
#pragma unroll
      for (int j = 0; j < 8; ++j)
        t8[j] = fmaxf(fmaxf(s0[j], s0[j + 8]), fmaxf(s1[j], s1[j + 8]));
      float pmax = fmaxf(fmaxf(fmaxf(t8[0], t8[1]), fmaxf(t8[2], t8[3])),
                         fmaxf(fmaxf(t8[4], t8[5]), fmaxf(t8[6], t8[7])));
      pmax = fmaxf(pmax, __shfl_xor(pmax, 32));
      float mold = m_run;
      bool defer = (__all(pmax <= m_run + 11.5416f) != 0);
      if (!defer) m_run = fmaxf(m_run, pmax);
#pragma unroll
      for (int j = 0; j < 16; ++j) s0[j] = vexp2(s0[j] - m_run);
#pragma unroll
      for (int j = 0; j < 16; ++j) s1[j] = vexp2(s1[j] - m_run);
      float q8[8];
#pragma unroll
      for (int j = 0; j < 8; ++j) q8[j] = (s0[j] + s0[j + 8]) + (s1[j] + s1[j + 8]);
      float rs = ((q8[0] + q8[1]) + (q8[2] + q8[3])) + ((q8[4] + q8[5]) + (q8[6] + q8[7]));
      rs += __shfl_xor(rs, 32);
      if (!defer) {
        float resc = vexp2(mold - m_run);
        l_run = l_run * resc + rs;
#pragma unroll
        for (int r = 0; r < 16; ++r) {
          int qr = (r & 3) + 8 * (r >> 2) + 4 * hi;
          float f = __shfl(resc, qr, 32);
#pragma unroll
          for (int dt = 0; dt < 4; ++dt) acc[dt][r] *= f;
        }
      } else {
        l_run += rs;
      }
      bf16x8 pa[4];
      PACK(0, s0, 0) PACK(1, s0, 8) PACK(2, s1, 0) PACK(3, s1, 8)
      wg_barrier();
      if (kt < 31) attn_write(skA, svA, smem, krow, vrow, kcol, vc);  // tile kt+1 (even buf)
      wg_barrier();
      __builtin_amdgcn_s_setprio(1);
      if (kt < 31) qk_step(smem, qf, lc, hi, s0, s1);
      const char* Vb_ = smem + 32768 + 16384;  // buf1 V (tile kt, odd)
#pragma unroll
      for (int ks = 0; ks < 4; ++ks) {
        int cb = ks * 32 + hi * 16;
#pragma unroll
        for (int dt = 0; dt < 4; ++dt) {
          int vr = dt * 32 + lc;
          bf16x8 vb = *(const bf16x8*)(Vb_ + vr * 128 + (cb ^ ((vr & 7) << 4)));
          acc[dt] = __builtin_amdgcn_mfma_f32_32x32x16_bf16(pa[ks], vb, acc[dt], 0, 0, 0);
        }
      }
      __builtin_amdgcn_s_setprio(0);
    }
  }
#undef PACK

  // epilogue: O[q=crow(r,hi)][dd=dt*32+lc] / l_run[q] -> att[b, s, h*128+dd] (bf16)
  int b = bh >> 3, h = bh & 7;
#pragma unroll
  for (int r = 0; r < 16; ++r) {
    int qr = (r & 3) + 8 * (r >> 2) + 4 * hi;
    float linv = 1.f / __shfl(l_run, qr, 32);
    unsigned short* orow = att + ((b * 2048 + (q0 + qr)) * 8 + h) * 128 + lc;
#pragma unroll
    for (int dt = 0; dt < 4; ++dt) orow[dt * 32] = f2bf(acc[dt][r] * linv);
  }
}

// 64x64 output tile from As(64x128) x Bs(64x128)^T, both swizzled
__device__ __forceinline__ void mfma_64x64(const unsigned short* As, const unsigned short* Bs,
                                           int w, int l, f32x4 acc[4]) {
  int lc = l & 15, kg = l >> 4;
#pragma unroll
  for (int kc = 0; kc < 4; ++kc) {
    int ar = w * 16 + lc;
    bf16x8 a = *(const bf16x8*)((const char*)As + ar * 256 + ((kc * 64 + kg * 16) ^ ((ar & 7) << 4)));
#pragma unroll
    for (int tt = 0; tt < 4; ++tt) {
      int br = tt * 16 + lc;
      bf16x8 b = *(const bf16x8*)((const char*)Bs + br * 256 + ((kc * 64 + kg * 16) ^ ((br & 7) << 4)));
      acc[tt] = __builtin_amdgcn_mfma_f32_16x16x32_bf16(a, b, acc[tt], 0, 0, 0);
    }
  }
}

// ---------------- output projection: out = att @ Wo + bo (fp32 out) ----------------
__global__ __launch_bounds__(256) void out_proj_kernel(const unsigned short* __restrict__ att,
    const unsigned short* __restrict__ Wot, const float* __restrict__ bo,
    float* __restrict__ out) {
  __shared__ unsigned short As[64 * 128], Bs[64 * 128];
  int m0 = blockIdx.x * 64, n0 = blockIdx.y * 64;
  int t = threadIdx.x, w = t >> 6, l = t & 63, lc = l & 15, kg = l >> 4;
  f32x4 acc[4];
#pragma unroll
  for (int i = 0; i < 4; ++i) acc[i] = (f32x4){0.f, 0.f, 0.f, 0.f};
  f32x4 ra[4], rb[4];
#pragma unroll
  for (int it = 0; it < 4; ++it) {
    int c = t + it * 256, row = c >> 4, col = c & 15;
    ra[it] = *(const f32x4*)(att + (m0 + row) * 1024 + col * 8);
    rb[it] = *(const f32x4*)(Wot + (n0 + row) * 1024 + col * 8);
  }
  for (int kt = 0; kt < 8; ++kt) {
    if (kt) wg_barrier();
#pragma unroll
    for (int it = 0; it < 4; ++it) {
      int c = t + it * 256, row = c >> 4, col = c & 15;
      *(f32x4*)((char*)As + row * 256 + ((col * 16) ^ ((row & 7) << 4))) = ra[it];
      *(f32x4*)((char*)Bs + row * 256 + ((col * 16) ^ ((row & 7) << 4))) = rb[it];
    }
    wg_barrier();
    if (kt < 7) {
#pragma unroll
      for (int it = 0; it < 4; ++it) {
        int c = t + it * 256, row = c >> 4, col = c & 15;
        ra[it] = *(const f32x4*)(att + (m0 + row) * 1024 + (kt + 1) * 128 + col * 8);
        rb[it] = *(const f32x4*)(Wot + (n0 + row) * 1024 + (kt + 1) * 128 + col * 8);
      }
    }
    mfma_64x64(As, Bs, w, l, acc);
  }
#pragma unroll
  for (int tt = 0; tt < 4; ++tt)
#pragma unroll
    for (int e = 0; e < 4; ++e) {
      int m = m0 + w * 16 + kg * 4 + e;
      int n = n0 + tt * 16 + lc;
      out[m * 128 + n] = acc[tt][e] + bo[n];
    }
}

extern "C" void kernel_launch(void* const* d_in, const int* in_sizes, int n_in,
                              void* d_out, int out_size, void* d_ws, size_t ws_size,
                              hipStream_t stream) {
  const float* x  = (const float*)d_in[0];
  const float* Wq = (const float*)d_in[1];
  const float* Wk = (const float*)d_in[2];
  const float* Wv = (const float*)d_in[3];
  const float* Wo = (const float*)d_in[4];
  const float* bo = (const float*)d_in[5];
  float* out = (float*)d_out;
  char* ws = (char*)d_ws;
  unsigned short* xb  = (unsigned short*)(ws);
  unsigned short* Wtq = (unsigned short*)(ws + (2u << 20));
  unsigned short* Wtk = (unsigned short*)(ws + (2u << 20) + (256u << 10));
  unsigned short* Wtv = (unsigned short*)(ws + (2u << 20) + (512u << 10));
  unsigned short* Wot = (unsigned short*)(ws + (2u << 20) + (768u << 10));
  unsigned short* Qb  = (unsigned short*)(ws + (3u << 20));
  unsigned short* Kb  = (unsigned short*)(ws + (3u << 20) + (16u << 20));
  unsigned short* Vt  = (unsigned short*)(ws + (3u << 20) + (32u << 20));
  unsigned short* att = (unsigned short*)(ws + (3u << 20) + (48u << 20));

  hipLaunchKernelGGL(prep_kernel, dim3(640), dim3(256), 0, stream,
                     x, Wq, Wk, Wv, Wo, xb, Wtq, Wtk, Wtv, Wot);
  hipLaunchKernelGGL(qkv_kernel, dim3(128, 16), dim3(256), 0, stream,
                     xb, Wtq, Wtk, Wtv, Qb, Kb, Vt);
  hipLaunchKernelGGL(attn_kernel, dim3(512), dim3(256), 0, stream,
                     Qb, Kb, Vt, att);
  hipLaunchKernelGGL(out_proj_kernel, dim3(128, 2), dim3(256), 0, stream,
                     att, Wot, bo, out);
}

// Round 9
// 170.316 us; speedup vs baseline: 2.1408x; 1.2718x over previous
//
#include <hip/hip_runtime.h>

// MHSA fused pipeline: B=4 S=2048 D=128 H=8. fp32 in/out, bf16 MFMA internally.
// ws layout: xb(2MB) Wtq/Wtk/Wtv/Wot(256KB ea) | Qb(16MB) Kb(16MB) Vt(16MB) att(16MB)
// Softmax runs in log2 domain: Q projection is pre-scaled by 128^-0.25 * log2(e).
// Barriers: raw s_barrier + lgkmcnt(0) only (NO vmcnt drain). Single staging reg set
// (R4 proven 124 VGPR, no spill); loads for tile kt+2 issue right after the ds_write
// of tile kt+1 and stay in flight across both barriers -> full iteration of lead.

typedef __attribute__((ext_vector_type(8))) short bf16x8;
typedef __attribute__((ext_vector_type(4))) float f32x4;
typedef __attribute__((ext_vector_type(16))) float f32x16;
typedef __attribute__((ext_vector_type(4))) int i32x4;

#define LOG2E 1.4426950408889634f

__device__ __forceinline__ void wg_barrier() {   // __syncthreads minus the vmcnt(0) drain
  asm volatile("s_waitcnt lgkmcnt(0)" ::: "memory");
  __builtin_amdgcn_s_barrier();
}

__device__ __forceinline__ unsigned short f2bf(float f) {
  unsigned u = __builtin_bit_cast(unsigned, f);
  return (unsigned short)((u + 0x7fffu + ((u >> 16) & 1u)) >> 16);
}

__device__ __forceinline__ unsigned cvtpk(float lo, float hi) {
  unsigned r;
  asm("v_cvt_pk_bf16_f32 %0, %1, %2" : "=v"(r) : "v"(lo), "v"(hi));
  return r;
}

__device__ __forceinline__ float vexp2(float x) {  // raw v_exp_f32 (2^x)
  float r;
  asm("v_exp_f32 %0, %1" : "=v"(r) : "v"(x));
  return r;
}

// ---------------- prep: x -> bf16 (vectorized); W transposes via LDS tiles ----------------
__global__ __launch_bounds__(256) void prep_kernel(const float* __restrict__ x,
    const float* __restrict__ Wq, const float* __restrict__ Wk, const float* __restrict__ Wv,
    const float* __restrict__ Wo,
    unsigned short* __restrict__ xb, unsigned short* __restrict__ Wtq,
    unsigned short* __restrict__ Wtk, unsigned short* __restrict__ Wtv,
    unsigned short* __restrict__ Wot) {
  __shared__ float tl[64][68];
  int bid = blockIdx.x, t = threadIdx.x;
  if (bid < 512) {
    int idx = (bid * 256 + t) * 8;
    f32x4 a = *(const f32x4*)(x + idx);
    f32x4 b = *(const f32x4*)(x + idx + 4);
    i32x4 o;
    o[0] = (int)cvtpk(a[0], a[1]); o[1] = (int)cvtpk(a[2], a[3]);
    o[2] = (int)cvtpk(b[0], b[1]); o[3] = (int)cvtpk(b[2], b[3]);
    *(i32x4*)(xb + idx) = o;
    return;
  }
  int tb = bid - 512;
  int which = tb >> 5, tile = tb & 31;
  const float* in; unsigned short* out; int K, N, kt_, nt_;
  if (which == 0)      { in = Wq; out = Wtq; }
  else if (which == 1) { in = Wk; out = Wtk; }
  else if (which == 2) { in = Wv; out = Wtv; }
  else                 { in = Wo; out = Wot; }
  if (which < 3) { K = 128;  N = 1024; kt_ = tile >> 4; nt_ = tile & 15; }
  else           { K = 1024; N = 128;  kt_ = tile >> 1; nt_ = tile & 1; }
  int k0 = kt_ * 64, n0 = nt_ * 64;
  int tr = t >> 4, tc = (t & 15) * 4;
#pragma unroll
  for (int i = 0; i < 4; ++i) {
    f32x4 v = *(const f32x4*)(in + (k0 + tr + i * 16) * N + n0 + tc);
#pragma unroll
    for (int j = 0; j < 4; ++j) tl[tc + j][tr + i * 16] = v[j];
  }
  __syncthreads();
  int n = t >> 2, c0 = (t & 3) * 16;
  i32x4 o1, o2;
#pragma unroll
  for (int j = 0; j < 4; ++j) o1[j] = (int)cvtpk(tl[n][c0 + 2 * j], tl[n][c0 + 2 * j + 1]);
#pragma unroll
  for (int j = 0; j < 4; ++j) o2[j] = (int)cvtpk(tl[n][c0 + 8 + 2 * j], tl[n][c0 + 9 + 2 * j]);
  *(i32x4*)(out + (n0 + n) * K + k0 + c0) = o1;
  *(i32x4*)(out + (n0 + n) * K + k0 + c0 + 8) = o2;
}

// ---------------- staging helpers (row = 128 bf16 = 256B swizzled) ----------------
__device__ __forceinline__ void stage_64x128(unsigned short* dst, const unsigned short* gsrc, int t) {
#pragma unroll
  for (int it = 0; it < 4; ++it) {
    int c = t + it * 256, row = c >> 4, col = c & 15;
    *(f32x4*)((char*)dst + row * 256 + ((col * 16) ^ ((row & 7) << 4))) =
        *(const f32x4*)(gsrc + row * 128 + col * 8);
  }
}

__device__ __forceinline__ void prefetch4(f32x4* r, const unsigned short* gsrc, int t) {
#pragma unroll
  for (int it = 0; it < 4; ++it) {
    int c = t + it * 256, row = c >> 4, col = c & 15;
    r[it] = *(const f32x4*)(gsrc + row * 128 + col * 8);
  }
}

__device__ __forceinline__ void write4(unsigned short* dst, const f32x4* r, int t) {
#pragma unroll
  for (int it = 0; it < 4; ++it) {
    int c = t + it * 256, row = c >> 4, col = c & 15;
    *(f32x4*)((char*)dst + row * 256 + ((col * 16) ^ ((row & 7) << 4))) = r[it];
  }
}

// MI*16 x NI*16 tile from As/Bs (both swizzled 64x128), K=128
template<int MI, int NI>
__device__ __forceinline__ void mma_t(const unsigned short* As, const unsigned short* Bs,
                                      int am0, int bn0, int l, f32x4 (&acc)[MI][NI]) {
  int lc = l & 15, kg = l >> 4;
#pragma unroll
  for (int kc = 0; kc < 4; ++kc) {
    bf16x8 a[MI], b[NI];
#pragma unroll
    for (int mi = 0; mi < MI; ++mi) {
      int ar = am0 + mi * 16 + lc;
      a[mi] = *(const bf16x8*)((const char*)As + ar * 256 + ((kc * 64 + kg * 16) ^ ((ar & 7) << 4)));
    }
#pragma unroll
    for (int ni = 0; ni < NI; ++ni) {
      int br = bn0 + ni * 16 + lc;
      b[ni] = *(const bf16x8*)((const char*)Bs + br * 256 + ((kc * 64 + kg * 16) ^ ((br & 7) << 4)));
    }
#pragma unroll
    for (int mi = 0; mi < MI; ++mi)
#pragma unroll
      for (int ni = 0; ni < NI; ++ni)
        acc[mi][ni] = __builtin_amdgcn_mfma_f32_16x16x32_bf16(a[mi], b[ni], acc[mi][ni], 0, 0, 0);
  }
}

// ---------------- merged QKV projection: 64x64 tiles, grid (128,16) ----------------
__global__ __launch_bounds__(256, 4) void qkv_kernel(const unsigned short* __restrict__ xb,
    const unsigned short* __restrict__ Wtq, const unsigned short* __restrict__ Wtk,
    const unsigned short* __restrict__ Wtv,
    unsigned short* __restrict__ Qb, unsigned short* __restrict__ Kb,
    unsigned short* __restrict__ Vt) {
  __shared__ unsigned short Xs[64 * 128], Ws[64 * 128];
  int m0 = blockIdx.x * 64, n0 = blockIdx.y * 64;
  int t = threadIdx.x, w = t >> 6, l = t & 63;
  int wm = w & 1, wn = w >> 1, lc = l & 15, kg = l >> 4;
  stage_64x128(Xs, xb + m0 * 128, t);
  stage_64x128(Ws, Wtq + n0 * 128, t);
  wg_barrier();

  f32x4 rw[4];
  prefetch4(rw, Wtk + n0 * 128, t);   // stays in flight (no vmcnt drain at barriers)

  f32x4 acc[2][2];
#pragma unroll
  for (int mi = 0; mi < 2; ++mi)
#pragma unroll
    for (int ni = 0; ni < 2; ++ni) acc[mi][ni] = (f32x4){0.f, 0.f, 0.f, 0.f};
  mma_t<2, 2>(Xs, Ws, wm * 32, wn * 32, l, acc);
  const float qscale = 0.29730177875068026f * LOG2E;  // 128^-0.25 * log2(e)
#pragma unroll
  for (int mi = 0; mi < 2; ++mi)
#pragma unroll
    for (int ni = 0; ni < 2; ++ni)
#pragma unroll
      for (int e = 0; e < 4; ++e) {
        int m = m0 + wm * 32 + mi * 16 + kg * 4 + e;
        int n = n0 + wn * 32 + ni * 16 + lc;
        int b = m >> 11, s = m & 2047, h = n >> 7, d = n & 127;
        Qb[((b * 8 + h) * 2048 + s) * 128 + d] = f2bf(acc[mi][ni][e] * qscale);
      }
  wg_barrier();
  write4(Ws, rw, t);                  // counted vmcnt wait happens here via reg dep
  wg_barrier();
  prefetch4(rw, Wtv + n0 * 128, t);

#pragma unroll
  for (int mi = 0; mi < 2; ++mi)
#pragma unroll
    for (int ni = 0; ni < 2; ++ni) acc[mi][ni] = (f32x4){0.f, 0.f, 0.f, 0.f};
  mma_t<2, 2>(Xs, Ws, wm * 32, wn * 32, l, acc);
  const float kscale = 0.29730177875068026f;
#pragma unroll
  for (int mi = 0; mi < 2; ++mi)
#pragma unroll
    for (int ni = 0; ni < 2; ++ni)
#pragma unroll
      for (int e = 0; e < 4; ++e) {
        int m = m0 + wm * 32 + mi * 16 + kg * 4 + e;
        int n = n0 + wn * 32 + ni * 16 + lc;
        int b = m >> 11, s = m & 2047, h = n >> 7, d = n & 127;
        Kb[((b * 8 + h) * 2048 + s) * 128 + d] = f2bf(acc[mi][ni][e] * kscale);
      }
  wg_barrier();
  write4(Ws, rw, t);
  wg_barrier();

  // V phase, operand-swapped: A = Wv^T rows (n), B = x rows (m) -> coalesced Vt write
#pragma unroll
  for (int mi = 0; mi < 2; ++mi)
#pragma unroll
    for (int ni = 0; ni < 2; ++ni) acc[mi][ni] = (f32x4){0.f, 0.f, 0.f, 0.f};
  mma_t<2, 2>(Ws, Xs, wm * 32, wn * 32, l, acc);
#pragma unroll
  for (int mi = 0; mi < 2; ++mi)
#pragma unroll
    for (int ni = 0; ni < 2; ++ni)
#pragma unroll
      for (int e = 0; e < 4; ++e) {
        int n = n0 + wm * 32 + mi * 16 + kg * 4 + e;
        int m = m0 + wn * 32 + ni * 16 + lc;
        int b = m >> 11, s = m & 2047, h = n >> 7, d = n & 127;
        Vt[((b * 8 + h) * 128 + d) * 2048 + s] = f2bf(acc[mi][ni][e]);
      }
}

// ---------------- flash attention: 4 waves x 32 q-rows, single-set pipelined staging ----
// Iter kt: softmax(kt) PACK | barrier | ds_write(tile kt+1) -> issue loads(kt+2) |
//          barrier(no drain) | setprio{ QK(kt+1) + PV(kt) }.
__device__ __forceinline__ void qk_step(const char* Kb_, const bf16x8* qf, int lc, int hi,
                                        f32x16& s0, f32x16& s1) {
#pragma unroll
  for (int j = 0; j < 16; ++j) { s0[j] = 0.f; s1[j] = 0.f; }
  int r1 = 32 + lc;
#pragma unroll
  for (int kc = 0; kc < 8; ++kc) {
    int cb = kc * 32 + hi * 16;
    bf16x8 k0 = *(const bf16x8*)(Kb_ + lc * 256 + (cb ^ ((lc & 7) << 4)));
    bf16x8 k1 = *(const bf16x8*)(Kb_ + r1 * 256 + (cb ^ ((r1 & 7) << 4)));
    s0 = __builtin_amdgcn_mfma_f32_32x32x16_bf16(k0, qf[kc], s0, 0, 0, 0);
    s1 = __builtin_amdgcn_mfma_f32_32x32x16_bf16(k1, qf[kc], s1, 0, 0, 0);
  }
}

__device__ __forceinline__ void attn_load(f32x4 (&sk)[4], f32x4 (&sv)[4],
    const unsigned short* Kp, const unsigned short* Vp, int kv0,
    const int (&krow)[4], const int (&vrow)[4], int kcol, int vc) {
#pragma unroll
  for (int i = 0; i < 4; ++i) {
    sk[i] = *(const f32x4*)(Kp + (kv0 + krow[i]) * 128 + kcol * 8);
    sv[i] = *(const f32x4*)(Vp + vrow[i] * 2048 + kv0 + vc * 8);
  }
}

__device__ __forceinline__ void attn_write(const f32x4 (&sk)[4], const f32x4 (&sv)[4],
    char* base, const int (&krow)[4], const int (&vrow)[4], int kcol, int vc) {
#pragma unroll
  for (int i = 0; i < 4; ++i) {
    *(f32x4*)(base + krow[i] * 256 + ((kcol * 16) ^ ((krow[i] & 7) << 4))) = sk[i];
    *(f32x4*)(base + 16384 + vrow[i] * 128 + ((vc * 16) ^ ((vrow[i] & 7) << 4))) = sv[i];
  }
}

__global__ __launch_bounds__(256, 2) void attn_kernel(const unsigned short* __restrict__ Qb,
    const unsigned short* __restrict__ Kb, const unsigned short* __restrict__ Vt,
    unsigned short* __restrict__ att) {
  __shared__ __align__(16) char smem[65536];  // buf b at b*32768: K 64x256B | V^T 128x128B
  int bid = blockIdx.x;
  int fid = (bid & 7) * 64 + (bid >> 3);      // XCD swizzle (512 % 8 == 0 -> bijective)
  int bh = fid >> 4, qt = fid & 15;
  const unsigned short* Qp = Qb + bh * 2048 * 128;
  const unsigned short* Kp = Kb + bh * 2048 * 128;
  const unsigned short* Vp = Vt + bh * 128 * 2048;
  int t = threadIdx.x, w = t >> 6, l = t & 63, lc = l & 31, hi = l >> 5;
  int q0 = qt * 128 + w * 32;

  // Q fragments (B-operand): lane l -> Q[q0+lc][kc*16 + hi*8 + j]
  bf16x8 qf[8];
  {
    const unsigned short* qr_ = Qp + (q0 + lc) * 128 + hi * 8;
#pragma unroll
    for (int kc = 0; kc < 8; ++kc) qf[kc] = *(const bf16x8*)(qr_ + kc * 16);
  }

  int kcol = l & 15, vc = l & 7;
  int krow[4], vrow[4];
#pragma unroll
  for (int i = 0; i < 4; ++i) { krow[i] = w * 16 + i * 4 + (l >> 4); vrow[i] = w * 32 + i * 8 + (l >> 3); }

  f32x16 acc[4];
#pragma unroll
  for (int i = 0; i < 4; ++i)
#pragma unroll
    for (int j = 0; j < 16; ++j) acc[i][j] = 0.f;
  float m_run = -1e30f, l_run = 0.f;

  f32x4 sk[4], sv[4];
  // prologue: tile0 -> buf0; tile1 loads in flight; QK(0)
  attn_load(sk, sv, Kp, Vp, 0, krow, vrow, kcol, vc);
  attn_write(sk, sv, smem, krow, vrow, kcol, vc);
  attn_load(sk, sv, Kp, Vp, 64, krow, vrow, kcol, vc);
  wg_barrier();
  f32x16 s0, s1;
  qk_step(smem, qf, lc, hi, s0, s1);

#define PACK(ks, SX, o) { \
      unsigned x1 = cvtpk(SX[o], SX[(o) + 1]); \
      unsigned y1 = cvtpk(SX[(o) + 4], SX[(o) + 5]); \
      unsigned x2 = cvtpk(SX[(o) + 2], SX[(o) + 3]); \
      unsigned y2 = cvtpk(SX[(o) + 6], SX[(o) + 7]); \
      asm("v_permlane32_swap_b32 %0, %1" : "+v"(x1), "+v"(y1)); \
      asm("v_permlane32_swap_b32 %0, %1" : "+v"(x2), "+v"(y2)); \
      i32x4 pp; \
      pp[0] = (int)x1; pp[1] = (int)x2; pp[2] = (int)y1; pp[3] = (int)y2; \
      pa[ks] = __builtin_bit_cast(bf16x8, pp); }

#pragma unroll 1
  for (int kt = 0; kt < 32; ++kt) {
    int nb = (kt + 1) & 1;

    // ---- softmax(kt), log2 domain, tree reductions ----
    float t8[8];
#pragma unroll
    for (int j = 0; j < 8; ++j)
      t8[j] = fmaxf(fmaxf(s0[j], s0[j + 8]), fmaxf(s1[j], s1[j + 8]));
    float pmax = fmaxf(fmaxf(fmaxf(t8[0], t8[1]), fmaxf(t8[2], t8[3])),
                       fmaxf(fmaxf(t8[4], t8[5]), fmaxf(t8[6], t8[7])));
    pmax = fmaxf(pmax, __shfl_xor(pmax, 32));
    float mold = m_run;
    bool defer = (__all(pmax <= m_run + 11.5416f) != 0);   // T13 in log2 units
    if (!defer) m_run = fmaxf(m_run, pmax);
#pragma unroll
    for (int j = 0; j < 16; ++j) s0[j] = vexp2(s0[j] - m_run);
#pragma unroll
    for (int j = 0; j < 16; ++j) s1[j] = vexp2(s1[j] - m_run);
    float q8[8];
#pragma unroll
    for (int j = 0; j < 8; ++j) q8[j] = (s0[j] + s0[j + 8]) + (s1[j] + s1[j + 8]);
    float rs = ((q8[0] + q8[1]) + (q8[2] + q8[3])) + ((q8[4] + q8[5]) + (q8[6] + q8[7]));
    rs += __shfl_xor(rs, 32);
    if (!defer) {
      float resc = vexp2(mold - m_run);
      l_run = l_run * resc + rs;
#pragma unroll
      for (int r = 0; r < 16; ++r) {
        int qr = (r & 3) + 8 * (r >> 2) + 4 * hi;
        float f = __shfl(resc, qr, 32);
#pragma unroll
        for (int dt = 0; dt < 4; ++dt) acc[dt][r] *= f;
      }
    } else {
      l_run += rs;
    }

    // ---- pack P -> PV A-frags via cvt_pk + permlane32_swap (T12) ----
    bf16x8 pa[4];
    PACK(0, s0, 0) PACK(1, s0, 8) PACK(2, s1, 0) PACK(3, s1, 8)

    // ---- write tile kt+1 (waits counted vmcnt via sk/sv dep); issue loads kt+2 ----
    wg_barrier();   // all waves done reading buf[nb] (last read: PV(kt-1))
    if (kt < 31) {
      attn_write(sk, sv, smem + (nb << 15), krow, vrow, kcol, vc);
      if (kt < 30) attn_load(sk, sv, Kp, Vp, (kt + 2) * 64, krow, vrow, kcol, vc);
    }
    wg_barrier();   // buf[nb] visible; kt+2 loads remain in flight

    // ---- contiguous MFMA cluster: QK(kt+1) then PV(kt) ----
    __builtin_amdgcn_s_setprio(1);
    if (kt < 31) qk_step(smem + (nb << 15), qf, lc, hi, s0, s1);
    const char* Vb_ = smem + ((kt & 1) << 15) + 16384;
#pragma unroll
    for (int ks = 0; ks < 4; ++ks) {
      int cb = ks * 32 + hi * 16;
#pragma unroll
      for (int dt = 0; dt < 4; ++dt) {
        int vr = dt * 32 + lc;
        bf16x8 vb = *(const bf16x8*)(Vb_ + vr * 128 + (cb ^ ((vr & 7) << 4)));
        acc[dt] = __builtin_amdgcn_mfma_f32_32x32x16_bf16(pa[ks], vb, acc[dt], 0, 0, 0);
      }
    }
    __builtin_amdgcn_s_setprio(0);
  }
#undef PACK

  // epilogue: O[q=crow(r,hi)][dd=dt*32+lc] / l_run[q] -> att[b, s, h*128+dd] (bf16)
  int b = bh >> 3, h = bh & 7;
#pragma unroll
  for (int r = 0; r < 16; ++r) {
    int qr = (r & 3) + 8 * (r >> 2) + 4 * hi;
    float linv = 1.f / __shfl(l_run, qr, 32);
    unsigned short* orow = att + ((b * 2048 + (q0 + qr)) * 8 + h) * 128 + lc;
#pragma unroll
    for (int dt = 0; dt < 4; ++dt) orow[dt * 32] = f2bf(acc[dt][r] * linv);
  }
}

// 64x64 output tile from As(64x128) x Bs(64x128)^T, both swizzled
__device__ __forceinline__ void mfma_64x64(const unsigned short* As, const unsigned short* Bs,
                                           int w, int l, f32x4 acc[4]) {
  int lc = l & 15, kg = l >> 4;
#pragma unroll
  for (int kc = 0; kc < 4; ++kc) {
    int ar = w * 16 + lc;
    bf16x8 a = *(const bf16x8*)((const char*)As + ar * 256 + ((kc * 64 + kg * 16) ^ ((ar & 7) << 4)));
#pragma unroll
    for (int tt = 0; tt < 4; ++tt) {
      int br = tt * 16 + lc;
      bf16x8 b = *(const bf16x8*)((const char*)Bs + br * 256 + ((kc * 64 + kg * 16) ^ ((br & 7) << 4)));
      acc[tt] = __builtin_amdgcn_mfma_f32_16x16x32_bf16(a, b, acc[tt], 0, 0, 0);
    }
  }
}

// ---------------- output projection: out = att @ Wo + bo (fp32 out) ----------------
__global__ __launch_bounds__(256) void out_proj_kernel(const unsigned short* __restrict__ att,
    const unsigned short* __restrict__ Wot, const float* __restrict__ bo,
    float* __restrict__ out) {
  __shared__ unsigned short As[64 * 128], Bs[64 * 128];
  int m0 = blockIdx.x * 64, n0 = blockIdx.y * 64;
  int t = threadIdx.x, w = t >> 6, l = t & 63, lc = l & 15, kg = l >> 4;
  f32x4 acc[4];
#pragma unroll
  for (int i = 0; i < 4; ++i) acc[i] = (f32x4){0.f, 0.f, 0.f, 0.f};
  f32x4 ra[4], rb[4];
#pragma unroll
  for (int it = 0; it < 4; ++it) {
    int c = t + it * 256, row = c >> 4, col = c & 15;
    ra[it] = *(const f32x4*)(att + (m0 + row) * 1024 + col * 8);
    rb[it] = *(const f32x4*)(Wot + (n0 + row) * 1024 + col * 8);
  }
  for (int kt = 0; kt < 8; ++kt) {
    if (kt) wg_barrier();
#pragma unroll
    for (int it = 0; it < 4; ++it) {
      int c = t + it * 256, row = c >> 4, col = c & 15;
      *(f32x4*)((char*)As + row * 256 + ((col * 16) ^ ((row & 7) << 4))) = ra[it];
      *(f32x4*)((char*)Bs + row * 256 + ((col * 16) ^ ((row & 7) << 4))) = rb[it];
    }
    wg_barrier();
    if (kt < 7) {
#pragma unroll
      for (int it = 0; it < 4; ++it) {
        int c = t + it * 256, row = c >> 4, col = c & 15;
        ra[it] = *(const f32x4*)(att + (m0 + row) * 1024 + (kt + 1) * 128 + col * 8);
        rb[it] = *(const f32x4*)(Wot + (n0 + row) * 1024 + (kt + 1) * 128 + col * 8);
      }
    }
    mfma_64x64(As, Bs, w, l, acc);
  }
#pragma unroll
  for (int tt = 0; tt < 4; ++tt)
#pragma unroll
    for (int e = 0; e < 4; ++e) {
      int m = m0 + w * 16 + kg * 4 + e;
      int n = n0 + tt * 16 + lc;
      out[m * 128 + n] = acc[tt][e] + bo[n];
    }
}

extern "C" void kernel_launch(void* const* d_in, const int* in_sizes, int n_in,
                              void* d_out, int out_size, void* d_ws, size_t ws_size,
                              hipStream_t stream) {
  const float* x  = (const float*)d_in[0];
  const float* Wq = (const float*)d_in[1];
  const float* Wk = (const float*)d_in[2];
  const float* Wv = (const float*)d_in[3];
  const float* Wo = (const float*)d_in[4];
  const float* bo = (const float*)d_in[5];
  float* out = (float*)d_out;
  char* ws = (char*)d_ws;
  unsigned short* xb  = (unsigned short*)(ws);
  unsigned short* Wtq = (unsigned short*)(ws + (2u << 20));
  unsigned short* Wtk = (unsigned short*)(ws + (2u << 20) + (256u << 10));
  unsigned short* Wtv = (unsigned short*)(ws + (2u << 20) + (512u << 10));
  unsigned short* Wot = (unsigned short*)(ws + (2u << 20) + (768u << 10));
  unsigned short* Qb  = (unsigned short*)(ws + (3u << 20));
  unsigned short* Kb  = (unsigned short*)(ws + (3u << 20) + (16u << 20));
  unsigned short* Vt  = (unsigned short*)(ws + (3u << 20) + (32u << 20));
  unsigned short* att = (unsigned short*)(ws + (3u << 20) + (48u << 20));

  hipLaunchKernelGGL(prep_kernel, dim3(640), dim3(256), 0, stream,
                     x, Wq, Wk, Wv, Wo, xb, Wtq, Wtk, Wtv, Wot);
  hipLaunchKernelGGL(qkv_kernel, dim3(128, 16), dim3(256), 0, stream,
                     xb, Wtq, Wtk, Wtv, Qb, Kb, Vt);
  hipLaunchKernelGGL(attn_kernel, dim3(512), dim3(256), 0, stream,
                     Qb, Kb, Vt, att);
  hipLaunchKernelGGL(out_proj_kernel, dim3(128, 2), dim3(256), 0, stream,
                     att, Wot, bo, out);
}